// Round 14
// baseline (1744.464 us; speedup 1.0000x reference)
//
#include <hip/hip_runtime.h>
#include <stdint.h>

typedef unsigned short u16;
typedef __bf16 bf16x8 __attribute__((ext_vector_type(8)));
typedef float f32x4 __attribute__((ext_vector_type(4)));

static constexpr int NB  = 256;
static constexpr int NH  = 2048;
static constexpr int NF  = 1024;
static constexpr int NZ  = 512;
static constexpr int NT  = 16;
static constexpr int NTS = 32;
static constexpr int NG4 = 8192;
static constexpr int NBLK = 256;

// ---------- helpers ----------
__device__ __forceinline__ u16 f2bf(float f) {
  union { float f; uint32_t u; } x; x.f = f;
  uint32_t r = x.u + 0x7fffu + ((x.u >> 16) & 1u);
  return (u16)(r >> 16);
}
__device__ __forceinline__ float b2f(u16 v) {
  union { float f; uint32_t u; } c; c.u = (uint32_t)v << 16; return c.f;
}
__device__ __forceinline__ float sigm(float x) { return 1.f / (1.f + expf(-x)); }

__device__ __forceinline__ void gload16(const void* g, void* l) {
  __builtin_amdgcn_global_load_lds(
      (__attribute__((address_space(1))) void*)const_cast<void*>(g),
      (__attribute__((address_space(3))) void*)l, 16, 0, 0);
}

__device__ __forceinline__ unsigned aload(const unsigned* p) {
  return __hip_atomic_load(p, __ATOMIC_RELAXED, __HIP_MEMORY_SCOPE_AGENT);
}
__device__ __forceinline__ void astore(unsigned* p, unsigned v) {
  __hip_atomic_store(p, v, __ATOMIC_RELAXED, __HIP_MEMORY_SCOPE_AGENT);
}
__device__ __forceinline__ void t_st(float* p, float v) {
  __hip_atomic_store(p, v, __ATOMIC_RELAXED, __HIP_MEMORY_SCOPE_AGENT);
}
__device__ __forceinline__ void t_st32(uint32_t* p, uint32_t v) {
  __hip_atomic_store(p, v, __ATOMIC_RELAXED, __HIP_MEMORY_SCOPE_AGENT);
}

// vectorized cache-bypassing (sc0 sc1) ops (r8/r10/r11-proven)
__device__ __forceinline__ void tl4(const float* p, f32x4& v) {
  asm volatile("global_load_dwordx4 %0, %1, off sc0 sc1" : "=&v"(v) : "v"(p));
}
__device__ __forceinline__ void ts2(void* p, uint32_t lo, uint32_t hi) {
  uint2 d; d.x = lo; d.y = hi;
  asm volatile("global_store_dwordx2 %0, %1, off sc0 sc1" :: "v"(p), "v"(d) : "memory");
}
__device__ __forceinline__ void t_wait() {
  asm volatile("s_waitcnt vmcnt(0)" ::: "memory");
  __builtin_amdgcn_sched_barrier(0);
}

// ---------- grid barrier v3 (r7/r10/r11-proven) ----------
__device__ __forceinline__ void gsync(unsigned* flags, unsigned* rel, unsigned& epoch) {
  ++epoch;
  asm volatile("s_waitcnt vmcnt(0)" ::: "memory");
  __syncthreads();
  if (blockIdx.x == 0) {
    if (threadIdx.x > 0)
      while (aload(&flags[threadIdx.x]) < epoch) __builtin_amdgcn_s_sleep(1);
    __syncthreads();
    if (threadIdx.x == 0) astore(rel, epoch);
  } else if (threadIdx.x == 0) {
    astore(&flags[blockIdx.x], epoch);
    while (aload(rel) < epoch) __builtin_amdgcn_s_sleep(1);
  }
  __syncthreads();
}

// ---------- pipelined GEMM tile core, templated on row-fragments F ----------
template<int F>
__device__ __forceinline__ void gemm_core(const u16* __restrict__ A, const u16* __restrict__ W,
                                          int lda, int ldw, int niter, int wg,
                                          char* lds, f32x4 (&acc)[F][4]) {
  constexpr int BUF = F * 4096 + 4096;
  const int tid = threadIdx.x, lane = tid & 63, wave = tid >> 6;
  const int srow = lane >> 2;
  const int schunk = (((lane & 3) ^ ((lane >> 3) & 3)) << 3);
  const u16* ga = A + (size_t)(wave * (F * 16) + srow) * lda + schunk;
  const u16* gw = W + (size_t)(wave * wg + srow) * ldw + schunk;
  const size_t astep = (size_t)16 * lda;
  auto STAGE = [&](int idx) {
    const int koff = idx << 5;
    char* base = lds + (idx % 3) * BUF;
    char* ad = base + wave * (F * 1024);
#pragma unroll
    for (int k = 0; k < F; ++k) gload16(ga + koff + k * astep, ad + k * 1024);
    gload16(gw + koff, base + F * 4096 + wave * 1024);
  };
  int rA[F], rW[4];
  const int b15 = lane & 15, h4 = lane >> 4, rx = (b15 >> 1) & 3;
#pragma unroll
  for (int f = 0; f < F; ++f) rA[f] = (wave * (F * 16) + f * 16 + b15) * 64 + ((h4 ^ rx) << 4);
#pragma unroll
  for (int q = 0; q < 4; ++q) rW[q] = F * 4096 + (q * 16 + b15) * 64 + ((h4 ^ rx) << 4);

  const int npro = niter < 3 ? niter : 3;
  for (int j = 0; j < npro; ++j) STAGE(j);
  for (int i = 0; i < niter; ++i) {
    const int ahead = niter - 1 - i;
    if constexpr (F == 4) {
      if (ahead >= 2)      asm volatile("s_waitcnt vmcnt(10)" ::: "memory");
      else if (ahead == 1) asm volatile("s_waitcnt vmcnt(5)" ::: "memory");
      else                 asm volatile("s_waitcnt vmcnt(0)" ::: "memory");
    } else if constexpr (F == 2) {
      if (ahead >= 2)      asm volatile("s_waitcnt vmcnt(6)" ::: "memory");
      else if (ahead == 1) asm volatile("s_waitcnt vmcnt(3)" ::: "memory");
      else                 asm volatile("s_waitcnt vmcnt(0)" ::: "memory");
    } else {
      if (ahead >= 2)      asm volatile("s_waitcnt vmcnt(4)" ::: "memory");
      else if (ahead == 1) asm volatile("s_waitcnt vmcnt(2)" ::: "memory");
      else                 asm volatile("s_waitcnt vmcnt(0)" ::: "memory");
    }
    __builtin_amdgcn_sched_barrier(0);
    asm volatile("s_barrier" ::: "memory");
    __builtin_amdgcn_sched_barrier(0);
    const char* base = lds + (i % 3) * BUF;
    bf16x8 av[F], bv[4];
#pragma unroll
    for (int f = 0; f < F; ++f) av[f] = *(const bf16x8*)(base + rA[f]);
#pragma unroll
    for (int q = 0; q < 4; ++q) bv[q] = *(const bf16x8*)(base + rW[q]);
    asm volatile("s_waitcnt lgkmcnt(0)" ::: "memory");
    __builtin_amdgcn_sched_barrier(0);
    asm volatile("s_barrier" ::: "memory");
    __builtin_amdgcn_sched_barrier(0);
    if (i + 3 < niter) STAGE(i + 3);
#pragma unroll
    for (int f = 0; f < F; ++f)
#pragma unroll
      for (int q = 0; q < 4; ++q)
        acc[f][q] = __builtin_amdgcn_mfma_f32_16x16x32_bf16(av[f], bv[q], acc[f][q], 0, 0, 0);
  }
}

// ---------- LDS-staged vectorized tile flushes ----------
__device__ __forceinline__ void flush_u16(const char* tb, u16* dst, int rs, int m0, int n0) {
  __syncthreads();
  const int tid = threadIdx.x, row = tid >> 2, qt = tid & 3;
  const uint2* s = (const uint2*)(tb + row * 128 + qt * 32);
  u16* d = dst + (size_t)(m0 + row) * rs + n0 + qt * 16;
  ts2(d, s[0].x, s[0].y);
  ts2(d + 4, s[1].x, s[1].y);
  ts2(d + 8, s[2].x, s[2].y);
  ts2(d + 12, s[3].x, s[3].y);
}
__device__ __forceinline__ void flush_f32(const char* tb, float* dst, int rs, int m0, int n0) {
  __syncthreads();
  const int tid = threadIdx.x, row = tid >> 2, qt = tid & 3;
  const uint2* s = (const uint2*)(tb + row * 256 + qt * 64);
  float* d = dst + (size_t)(m0 + row) * rs + n0 + qt * 16;
#pragma unroll
  for (int i = 0; i < 8; ++i) ts2(d + i * 2, s[i].x, s[i].y);
}

// P0-only: write bias-added 256-row tile via scalar through-stores
__device__ __forceinline__ void wbias(float* of, const float* bias, int Nn, int n0,
                                      const f32x4 (&acc)[4][4]) {
  const int tid = threadIdx.x, lane = tid & 63, wave = tid >> 6;
  const int b15 = lane & 15, h4 = lane >> 4;
#pragma unroll
  for (int q = 0; q < 4; ++q) {
    const int n = n0 + q * 16 + b15;
    const float bb = bias[n];
#pragma unroll
    for (int f = 0; f < 4; ++f) {
      const int m = wave * 64 + f * 16 + h4 * 4;
#pragma unroll
      for (int r = 0; r < 4; ++r) t_st(&of[(size_t)(m + r) * Nn + n], acc[f][q][r] + bb);
    }
  }
}

// ---------- batched setup ----------
struct TJobs {
  const float* W[13]; u16* D[13];
  int N[13], klo[13], ntx[13], base[14];
  const float* h_i; u16* hi_bf; int hi_base;
};
__global__ __launch_bounds__(256) void setup_tr(TJobs j) {
  const int bid = blockIdx.x, t = threadIdx.x;
  if (bid >= j.hi_base) {
    int i = ((bid - j.hi_base) * 256 + t) * 4;
    float4 v = *(const float4*)(j.h_i + i);
    ushort4 o; o.x = f2bf(v.x); o.y = f2bf(v.y); o.z = f2bf(v.z); o.w = f2bf(v.w);
    *(ushort4*)(j.hi_bf + i) = o;
    return;
  }
  int k = 0;
  while (bid >= j.base[k + 1]) ++k;
  const int tix = bid - j.base[k];
  const int ntx = j.ntx[k];
  const int kk0 = (tix % ntx) * 32, n0 = (tix / ntx) * 32;
  const int N = j.N[k], k_lo = j.klo[k], k_len = ntx * 32;
  const float* W = j.W[k];
  u16* WT = j.D[k];
  __shared__ float tile[32][33];
  const int r = t >> 3, cg = t & 7;
  const float4 v = *(const float4*)(W + (size_t)(k_lo + kk0 + r) * N + n0 + cg * 4);
  tile[r][cg * 4 + 0] = v.x; tile[r][cg * 4 + 1] = v.y;
  tile[r][cg * 4 + 2] = v.z; tile[r][cg * 4 + 3] = v.w;
  __syncthreads();
  ushort4 o;
  o.x = f2bf(tile[cg * 4 + 0][r]);
  o.y = f2bf(tile[cg * 4 + 1][r]);
  o.z = f2bf(tile[cg * 4 + 2][r]);
  o.w = f2bf(tile[cg * 4 + 3][r]);
  *(ushort4*)(WT + (size_t)(n0 + r) * k_len + kk0 + cg * 4) = o;
}

// ---------- misc ----------
__global__ __launch_bounds__(256) void misc_k(const float* __restrict__ input_t,
                                              const float* alpha, const float* beta,
                                              const float* base_, const float* tw,
                                              const float* b5, const float* b6,
                                              const float* b8, const float* b9,
                                              float* __restrict__ lam_buf,
                                              float* __restrict__ out_it,
                                              float* __restrict__ out_te,
                                              float* __restrict__ bq) {
  const int bid = blockIdx.x, tid = threadIdx.x;
  if (bid < 16) {
    int i = bid * 256 + tid;
    int b = i >> 4, jj = i & 15;
    const float* row = input_t + b * NTS;
    float cur = row[16 + jj];
    float trig = 0.f;
    int lim = 16 + jj;
    for (int s = 0; s < lim; ++s) trig += expf(row[s] - cur);
    float lam = base_[0] + alpha[0] * beta[0] * trig;
    float x = lam * (2048.f * tw[0]);
    float dt = (x > 15.f) ? x : log1pf(expf(x));
    lam_buf[b * NT + jj] = lam;
    out_it[jj * NB + b] = cur;
    out_te[jj * NB + b] = cur + dt;
  } else {
    int i = (bid - 16) * 256 + tid;
    bq[i] = (i < 512) ? b5[i] : (i < 1024) ? b6[i - 512]
          : (i < 1536) ? b8[i - 1024] : b9[i - 1536];
  }
}

// ---------- the persistent decoder kernel ----------
struct PArgs {
  const u16 *WkzT, *WkyT, *WkmT, *WrT, *W1T, *W2T, *W3T, *W4T, *W56T, *W7T, *W89T, *hi_bf;
  const float *bl, *b1, *b2, *b3, *b4, *b7, *bq, *ninf, *npri, *lam;
  float *Gc, *H4c, *H7c, *R;
  u16 *Pgh;                      // [2][256 tiles][128*64] bf16 Wr partials
  u16 *hbfV, *zV, *yV, *sbfV, *y1V, *y2V, *hzV, *hzpV;
  float *o_ys, *o_mean, *o_logv, *o_zs, *o_zps;
  unsigned *flags, *rel;
};

__global__ __launch_bounds__(256) void persist(PArgs a) {
  __shared__ __attribute__((aligned(16))) char lds[3 * 20480];
  const int bid = blockIdx.x, tid = threadIdx.x;
  const int lane = tid & 63, wave = tid >> 6, b15 = lane & 15, h4 = lane >> 4;
  unsigned epoch = 0;
  float* Q    = a.R;
  float* Phz  = a.R + (size_t)4 * NB * 512;       // planes 0..2 used
  float* Phzp = a.R + (size_t)8 * NB * 512;       // planes 0..2
  char* tb = lds + 24576;

  const int g_mh = bid >> 7;
  const int g_c0 = (bid & 127) * 16;
  float cR[2][4];
#pragma unroll
  for (int f = 0; f < 2; ++f)
#pragma unroll
    for (int r = 0; r < 4; ++r) cR[f][r] = 0.f;

  // ---- P0 (r10-r13 verbatim)
  {
    if (bid < 144) {
      f32x4 acc[4][4] = {};
      if (bid < 128) {
        const int n0 = bid * 64;
        gemm_core<4>(a.hi_bf, a.WkmT + (size_t)n0 * 2048, 2048, 2048, 64, 16, lds, acc);
        wbias(a.Gc, a.bl, NG4, n0, acc);
      } else if (bid < 136) {
        const int n0 = (bid - 128) * 64;
        gemm_core<4>(a.hi_bf, a.W4T + (size_t)n0 * 6144, 2048, 6144, 64, 16, lds, acc);
        wbias(a.H4c, a.b4, NZ, n0, acc);
      } else {
        const int n0 = (bid - 136) * 64;
        gemm_core<4>(a.hi_bf, a.W7T + (size_t)n0 * 5120, 2048, 5120, 64, 16, lds, acc);
        wbias(a.H7c, a.b7, NZ, n0, acc);
      }
    } else {
      const int zt = (bid - 144) * 256 + tid, nthr = 112 * 256;
      for (int w = zt; w < NB * NH / 2; w += nthr) t_st32((uint32_t*)a.hbfV + w, 0u);
      for (int w = zt; w < NB * NZ / 2; w += nthr) t_st32((uint32_t*)a.zV + w, 0u);
      for (int w = zt; w < NB * NF / 2; w += nthr) t_st32((uint32_t*)a.yV + w, 0u);
    }
    gsync(a.flags, a.rel, epoch);
  }

  float GcR[2][4][4];
#pragma unroll
  for (int f = 0; f < 2; ++f)
#pragma unroll
    for (int q = 0; q < 4; ++q)
#pragma unroll
      for (int r = 0; r < 4; ++r) {
        const int m = g_mh * 128 + wave * 32 + f * 16 + h4 * 4 + r;
        GcR[f][q][r] = a.Gc[(size_t)m * NG4 + q * 2048 + g_c0 + b15];
      }

  for (int t = 0; t < NT; ++t) {
    u16* hbf_n = a.hbfV + (size_t)(t + 1) * NB * NH;
    const u16* z_t = a.zV + (size_t)t * NB * NZ;
    u16* z_n = a.zV + (size_t)(t + 1) * NB * NZ;
    const u16* yp = a.yV + (size_t)t * NB * NF;
    u16* yc = a.yV + (size_t)(t + 1) * NB * NF;
    u16* sbf = a.sbfV + (size_t)t * NB * NH;
    u16* y1bf = a.y1V + (size_t)t * NB * NF;
    u16* y2bf = a.y2V + (size_t)t * NB * NF;
    u16* hzbf = a.hzV + (size_t)t * NB * NZ;
    u16* hzpbf = a.hzpV + (size_t)t * NB * NZ;

    // Wr-precompute job for step t+1 (runs on idle blocks in PH3/PH4/PH5)
    auto wr_job = [&](int j) {
      if (t >= NT - 1) return;
      const int tile = j & 255, half = j >> 8;
      const int mh = tile >> 7, c0 = (tile & 127) * 16;
      f32x4 jac[2][4] = {};
      gemm_core<2>(hbf_n + (size_t)mh * 128 * 2048 + half * 1024,
                   a.WrT + (size_t)c0 * 2048 + half * 1024,
                   2048, 2048, 32, 2048, lds, jac);
      u16* tlj = (u16*)(lds + 36864);
#pragma unroll
      for (int f = 0; f < 2; ++f)
#pragma unroll
        for (int q = 0; q < 4; ++q)
#pragma unroll
          for (int r = 0; r < 4; ++r)
            tlj[(wave * 32 + f * 16 + h4 * 4 + r) * 64 + q * 16 + b15] = f2bf(jac[f][q][r]);
      __syncthreads();
      u16* dst = a.Pgh + ((size_t)half * 256 + tile) * 8192;
      const int row = tid >> 1, co = (tid & 1) * 32;
      const uint2* s = (const uint2*)(lds + 36864 + row * 128 + co * 2);
      u16* d = dst + row * 64 + co;
#pragma unroll
      for (int i = 0; i < 8; ++i) ts2(d + i * 4, s[i].x, s[i].y);
    };

    // ---- PH1: gates (z,yp) + precomputed Wr tiles + LSTM cell (256 blocks)
    {
      f32x4 acc[2][4] = {};
      gemm_core<2>(z_t + (size_t)g_mh * 128 * 512, a.WkzT + (size_t)g_c0 * 512,
                   512, 512, 16, 2048, lds, acc);
      gemm_core<2>(yp + (size_t)g_mh * 128 * 1024, a.WkyT + (size_t)g_c0 * 1024,
                   1024, 1024, 32, 2048, lds, acc);
      __syncthreads();
      if (t > 0) {
        // load this block's 2 Wr half-tiles (cache-bypassed) into LDS
        const float* t0 = (const float*)(a.Pgh + (size_t)bid * 8192);
        const float* t1 = (const float*)(a.Pgh + (size_t)(256 + bid) * 8192);
        f32x4 v0[4], v1[4];
#pragma unroll
        for (int i = 0; i < 4; ++i) tl4(t0 + tid * 16 + i * 4, v0[i]);
#pragma unroll
        for (int i = 0; i < 4; ++i) tl4(t1 + tid * 16 + i * 4, v1[i]);
        t_wait();
        f32x4* l0 = (f32x4*)(lds + tid * 64);
        f32x4* l1 = (f32x4*)(lds + 16384 + tid * 64);
#pragma unroll
        for (int i = 0; i < 4; ++i) { l0[i] = v0[i]; l1[i] = v1[i]; }
      }
      __syncthreads();
      const u16* T0 = (const u16*)lds;
      const u16* T1 = (const u16*)(lds + 16384);
      u16* tlh = (u16*)(lds + 36864);
      u16* tls = (u16*)(lds + 36864 + 4096);
#pragma unroll
      for (int f = 0; f < 2; ++f)
#pragma unroll
        for (int r = 0; r < 4; ++r) {
          const int ml = wave * 32 + f * 16 + h4 * 4 + r;
          const int m = g_mh * 128 + ml;
          float g4[4];
#pragma unroll
          for (int q = 0; q < 4; ++q) {
            float v = acc[f][q][r] + GcR[f][q][r];
            if (t > 0)
              v += b2f(T0[ml * 64 + q * 16 + b15]) + b2f(T1[ml * 64 + q * 16 + b15]);
            g4[q] = v;
          }
          const float cn = sigm(g4[1]) * cR[f][r] + sigm(g4[0]) * tanhf(g4[2]);
          const float hn = sigm(g4[3]) * tanhf(cn);
          cR[f][r] = a.lam[m * NT + t] * cn;
          tlh[ml * 16 + b15] = f2bf(hn);
          tls[ml * 16 + b15] = f2bf(cn);
        }
      __syncthreads();
      {
        const int row = tid >> 1, half = tid & 1;
        const char* srch = lds + 36864 + row * 32 + half * 16;
        uint2 u0 = *(const uint2*)srch;
        uint2 u1 = *(const uint2*)(srch + 8);
        u16* dh = hbf_n + (size_t)(g_mh * 128 + row) * NH + g_c0 + half * 8;
        ts2(dh, u0.x, u0.y);
        ts2(dh + 4, u1.x, u1.y);
        const char* srcs = lds + 36864 + 4096 + row * 32 + half * 16;
        uint2 s0 = *(const uint2*)srcs;
        uint2 s1 = *(const uint2*)(srcs + 8);
        u16* dsp = sbf + (size_t)(g_mh * 128 + row) * NH + g_c0 + half * 8;
        ts2(dsp, s0.x, s0.y);
        ts2(dsp + 4, s1.x, s1.y);
      }
      gsync(a.flags, a.rel, epoch);
    }

    // ---- PH2 (256 blocks): y1 ∥ hz-sbf(k2) ∥ hz-yp ∥ hzp-sbf(k2) ∥ hzp-yp (r13-verbatim)
    {
      if (bid < 64) {
        const int mt = bid >> 4, nt = bid & 15, m0 = mt * 64, n0 = nt * 64;
        f32x4 acc[1][4] = {};
        gemm_core<1>(hbf_n + (size_t)m0 * 2048, a.W1T + (size_t)n0 * 2048,
                     2048, 2048, 64, 16, lds, acc);
        u16* tl = (u16*)tb;
#pragma unroll
        for (int q = 0; q < 4; ++q) {
          const float bb = a.b1[n0 + q * 16 + b15];
#pragma unroll
          for (int r = 0; r < 4; ++r) {
            const int ml = wave * 16 + h4 * 4 + r;
            tl[ml * 64 + q * 16 + b15] = f2bf(fmaxf(acc[0][q][r] + bb, 0.f));
          }
        }
        flush_u16(tb, y1bf, NF, m0, n0);
      } else if (bid < 128) {
        const int s = bid - 64, mt = s >> 4, rest = s & 15, nt = rest & 7, k = rest >> 3;
        const int m0 = mt * 64, n0 = nt * 64;
        f32x4 acc[1][4] = {};
        gemm_core<1>(sbf + (size_t)m0 * 2048 + k * 1024,
                     a.W4T + 2048 + (size_t)n0 * 6144 + k * 1024,
                     2048, 6144, 32, 16, lds, acc);
        float* tf = (float*)tb;
#pragma unroll
        for (int q = 0; q < 4; ++q)
#pragma unroll
          for (int r = 0; r < 4; ++r)
            tf[(wave * 16 + h4 * 4 + r) * 64 + q * 16 + b15] = acc[0][q][r];
        flush_f32(tb, Phz + (size_t)k * NB * 512, 512, m0, n0);
      } else if (bid < 160) {
        const int s = bid - 128, mt = s >> 3, nt = s & 7, m0 = mt * 64, n0 = nt * 64;
        f32x4 acc[1][4] = {};
        gemm_core<1>(yp + (size_t)m0 * 1024, a.W4T + 5120 + (size_t)n0 * 6144,
                     1024, 6144, 32, 16, lds, acc);
        float* tf = (float*)tb;
#pragma unroll
        for (int q = 0; q < 4; ++q)
#pragma unroll
          for (int r = 0; r < 4; ++r)
            tf[(wave * 16 + h4 * 4 + r) * 64 + q * 16 + b15] = acc[0][q][r];
        flush_f32(tb, Phz + (size_t)2 * NB * 512, 512, m0, n0);
      } else if (bid < 224) {
        const int s = bid - 160, mt = s >> 4, rest = s & 15, nt = rest & 7, k = rest >> 3;
        const int m0 = mt * 64, n0 = nt * 64;
        f32x4 acc[1][4] = {};
        gemm_core<1>(sbf + (size_t)m0 * 2048 + k * 1024,
                     a.W7T + 2048 + (size_t)n0 * 5120 + k * 1024,
                     2048, 5120, 32, 16, lds, acc);
        float* tf = (float*)tb;
#pragma unroll
        for (int q = 0; q < 4; ++q)
#pragma unroll
          for (int r = 0; r < 4; ++r)
            tf[(wave * 16 + h4 * 4 + r) * 64 + q * 16 + b15] = acc[0][q][r];
        flush_f32(tb, Phzp + (size_t)k * NB * 512, 512, m0, n0);
      } else {
        const int s = bid - 224, mt = s >> 3, nt = s & 7, m0 = mt * 64, n0 = nt * 64;
        f32x4 acc[1][4] = {};
        gemm_core<1>(yp + (size_t)m0 * 1024, a.W7T + 4096 + (size_t)n0 * 5120,
                     1024, 5120, 32, 16, lds, acc);
        float* tf = (float*)tb;
#pragma unroll
        for (int q = 0; q < 4; ++q)
#pragma unroll
          for (int r = 0; r < 4; ++r)
            tf[(wave * 16 + h4 * 4 + r) * 64 + q * 16 + b15] = acc[0][q][r];
        flush_f32(tb, Phzp + (size_t)2 * NB * 512, 512, m0, n0);
      }
      gsync(a.flags, a.rel, epoch);
    }

    // ---- PH3: y2 (0-63) ∥ hzp-comb (64-95) ∥ Wr jobs 0-159 (96-255)
    {
      if (bid < 64) {
        const int mt = bid >> 4, nt = bid & 15, m0 = mt * 64, n0 = nt * 64;
        f32x4 acc[1][4] = {};
        gemm_core<1>(y1bf + (size_t)m0 * 1024, a.W2T + (size_t)n0 * 1024,
                     1024, 1024, 32, 16, lds, acc);
        u16* tl = (u16*)tb;
#pragma unroll
        for (int q = 0; q < 4; ++q) {
          const float bb = a.b2[n0 + q * 16 + b15];
#pragma unroll
          for (int r = 0; r < 4; ++r) {
            const int ml = wave * 16 + h4 * 4 + r;
            tl[ml * 64 + q * 16 + b15] = f2bf(fmaxf(acc[0][q][r] + bb, 0.f));
          }
        }
        flush_u16(tb, y2bf, NF, m0, n0);
      } else if (bid < 96) {
        const int cb = bid - 64;
        for (int p = 0; p < 4; ++p) {
          const int idx = ((p * 32 + cb) * 256 + tid) * 4;
          f32x4 v0, v1, v2;
          tl4(Phzp + idx, v0);
          tl4(Phzp + (size_t)NB * 512 + idx, v1);
          tl4(Phzp + (size_t)2 * NB * 512 + idx, v2);
          f32x4 c0 = *(const f32x4*)(a.H7c + idx);
          t_wait();
          f32x4 v = v0 + v1 + v2 + c0;
          u16 o[4];
#pragma unroll
          for (int r = 0; r < 4; ++r) o[r] = f2bf(fmaxf(v[r], 0.f));
          ts2(hzpbf + idx, (uint32_t)o[0] | ((uint32_t)o[1] << 16),
                           (uint32_t)o[2] | ((uint32_t)o[3] << 16));
        }
      } else {
        wr_job(bid - 96);
      }
      gsync(a.flags, a.rel, epoch);
    }

    // ---- PH4: y3 -> yc + o_ys (0-63) ∥ heads-pri -> Q (64-127) ∥ Wr jobs 160-287
    {
      if (bid < 64) {
        const int mt = bid >> 4, nt = bid & 15, m0 = mt * 64, n0 = nt * 64;
        f32x4 acc[1][4] = {};
        gemm_core<1>(y2bf + (size_t)m0 * 1024, a.W3T + (size_t)n0 * 1024,
                     1024, 1024, 32, 16, lds, acc);
        u16* tl = (u16*)tb;
#pragma unroll
        for (int q = 0; q < 4; ++q) {
          const int n = n0 + q * 16 + b15;
          const float bb = a.b3[n];
#pragma unroll
          for (int r = 0; r < 4; ++r) {
            const int ml = wave * 16 + h4 * 4 + r;
            const float v = fmaxf(acc[0][q][r] + bb, 0.f);
            tl[ml * 64 + q * 16 + b15] = f2bf(v);
            a.o_ys[((size_t)(m0 + ml) * NT + t) * NF + n] = v;
          }
        }
        flush_u16(tb, yc, NF, m0, n0);
      } else if (bid < 128) {
        const int s = bid - 64, mt = s >> 4, nt = s & 15, m0 = mt * 64, n0 = nt * 64;
        f32x4 acc[1][4] = {};
        gemm_core<1>(hzpbf + (size_t)m0 * 512, a.W89T + (size_t)n0 * 512,
                     512, 512, 16, 16, lds, acc);
        float* tf = (float*)tb;
#pragma unroll
        for (int q = 0; q < 4; ++q) {
          const float bb = a.bq[1024 + n0 + q * 16 + b15];
#pragma unroll
          for (int r = 0; r < 4; ++r)
            tf[(wave * 16 + h4 * 4 + r) * 64 + q * 16 + b15] = fmaxf(acc[0][q][r] + bb, 0.f);
        }
        const int plane = 2 + (n0 >> 9), col0 = n0 & 511;
        flush_f32(tb, Q + (size_t)plane * NB * 512, 512, m0, col0);
      } else {
        wr_job(160 + bid - 128);
      }
      gsync(a.flags, a.rel, epoch);
    }

    // ---- PH5: hzB (yc@W4b) + FUSED hz-comb -> hzbf (0-31, vectorized) ∥ Wr jobs 288-511
    {
      if (bid < 32) {
        const int mt = bid >> 3, nt = bid & 7, m0 = mt * 64, n0 = nt * 64;
        f32x4 acc[1][4] = {};
        gemm_core<1>(yc + (size_t)m0 * 1024, a.W4T + 4096 + (size_t)n0 * 6144,
                     1024, 6144, 32, 16, lds, acc);
        float* tf = (float*)tb;
#pragma unroll
        for (int q = 0; q < 4; ++q)
#pragma unroll
          for (int r = 0; r < 4; ++r)
            tf[(wave * 16 + h4 * 4 + r) * 64 + q * 16 + b15] = acc[0][q][r];
        __syncthreads();
        const int row = tid >> 2, qt = tid & 3;
        const size_t base = (size_t)(m0 + row) * 512 + n0 + qt * 16;
        f32x4 p0[4], p1[4], p2[4];
#pragma unroll
        for (int i = 0; i < 4; ++i) {
          tl4(Phz + base + i * 4, p0[i]);
          tl4(Phz + (size_t)NB * 512 + base + i * 4, p1[i]);
          tl4(Phz + (size_t)2 * NB * 512 + base + i * 4, p2[i]);
        }
        t_wait();
#pragma unroll
        for (int i = 0; i < 4; ++i) {
          f32x4 v = *(const f32x4*)(tf + row * 64 + qt * 16 + i * 4)
                  + p0[i] + p1[i] + p2[i]
                  + *(const f32x4*)(a.H4c + base + i * 4);
          u16 o[4];
#pragma unroll
          for (int r = 0; r < 4; ++r) o[r] = f2bf(fmaxf(v[r], 0.f));
          ts2(hzbf + base + i * 4, (uint32_t)o[0] | ((uint32_t)o[1] << 16),
                                   (uint32_t)o[2] | ((uint32_t)o[3] << 16));
        }
      } else {
        wr_job(288 + bid - 32);
      }
      gsync(a.flags, a.rel, epoch);
    }

    // ---- PH6: heads-inf -> Q planes 0/1 (64 blocks)
    {
      if (bid < 64) {
        const int mt = bid >> 4, nt = bid & 15, m0 = mt * 64, n0 = nt * 64;
        f32x4 acc[1][4] = {};
        gemm_core<1>(hzbf + (size_t)m0 * 512, a.W56T + (size_t)n0 * 512,
                     512, 512, 16, 16, lds, acc);
        float* tf = (float*)tb;
#pragma unroll
        for (int q = 0; q < 4; ++q) {
          const float bb = a.bq[n0 + q * 16 + b15];
#pragma unroll
          for (int r = 0; r < 4; ++r)
            tf[(wave * 16 + h4 * 4 + r) * 64 + q * 16 + b15] = fmaxf(acc[0][q][r] + bb, 0.f);
        }
        const int plane = n0 >> 9, col0 = n0 & 511;
        flush_f32(tb, Q + (size_t)plane * NB * 512, 512, m0, col0);
      }
      gsync(a.flags, a.rel, epoch);
    }

    // ---- PH7: sample z/zp (128 blocks) — r13-verbatim
    {
      if (bid < 128) {
        const int g2 = bid * 256 + tid;
        const int i = g2 * 4, m = i >> 9, jj = i & 511;
        const float* qb = Q + (size_t)m * 512 + jj;
        f32x4 mean, logv, mpv, lpv;
        tl4(qb, mean);
        tl4(qb + (size_t)NB * 512, logv);
        tl4(qb + (size_t)2 * NB * 512, mpv);
        tl4(qb + (size_t)3 * NB * 512, lpv);
        f32x4 nI = *(const f32x4*)(a.ninf + (size_t)t * NB * NZ + i);
        f32x4 nP = *(const f32x4*)(a.npri + (size_t)t * NB * NZ + i);
        t_wait();
        f32x4 z, zp;
        u16 zq[4];
#pragma unroll
        for (int r = 0; r < 4; ++r) {
          z[r] = fmaf(nI[r], sqrtf(expf(logv[r])), mean[r]);
          zp[r] = fmaf(nP[r], sqrtf(expf(lpv[r])), mpv[r]);
          zq[r] = f2bf(z[r]);
        }
        const size_t oo = ((size_t)m * NT + t) * NZ + jj;
        *(f32x4*)(a.o_mean + oo) = mean;
        *(f32x4*)(a.o_logv + oo) = logv;
        *(f32x4*)(a.o_zs + oo) = z;
        *(f32x4*)(a.o_zps + oo) = zp;
        ts2(z_n + i, (uint32_t)zq[0] | ((uint32_t)zq[1] << 16),
                     (uint32_t)zq[2] | ((uint32_t)zq[3] << 16));
      }
      gsync(a.flags, a.rel, epoch);
    }
  }
}

// ---------- launcher ----------
extern "C" void kernel_launch(void* const* d_in, const int* in_sizes, int n_in,
                              void* d_out, int out_size, void* d_ws, size_t ws_size,
                              hipStream_t stream) {
  const float* h_i  = (const float*)d_in[0];
  const float* in_t = (const float*)d_in[1];
  const float* Wk   = (const float*)d_in[2];
  const float* Wr   = (const float*)d_in[3];
  const float* bl   = (const float*)d_in[4];
  const float* W1 = (const float*)d_in[5];  const float* b1 = (const float*)d_in[6];
  const float* W2 = (const float*)d_in[7];  const float* b2 = (const float*)d_in[8];
  const float* W3 = (const float*)d_in[9];  const float* b3 = (const float*)d_in[10];
  const float* W4 = (const float*)d_in[11]; const float* b4 = (const float*)d_in[12];
  const float* W5 = (const float*)d_in[13]; const float* b5 = (const float*)d_in[14];
  const float* W6 = (const float*)d_in[15]; const float* b6 = (const float*)d_in[16];
  const float* W7 = (const float*)d_in[17]; const float* b7 = (const float*)d_in[18];
  const float* W8 = (const float*)d_in[19]; const float* b8 = (const float*)d_in[20];
  const float* W9 = (const float*)d_in[21]; const float* b9 = (const float*)d_in[22];
  const float* alpha = (const float*)d_in[23];
  const float* beta  = (const float*)d_in[24];
  const float* base_ = (const float*)d_in[25];
  const float* tw    = (const float*)d_in[26];
  const float* ninf  = (const float*)d_in[27];
  const float* npri  = (const float*)d_in[28];
  float* out = (float*)d_out;
  (void)in_sizes; (void)n_in; (void)out_size; (void)ws_size;

  char* wsb = (char*)d_ws;
  size_t off = 0;
  auto alloc = [&](size_t bytes) -> void* {
    void* p = wsb + off;
    off += (bytes + 255) & ~(size_t)255;
    return p;
  };
  u16* WkzT = (u16*)alloc((size_t)NG4 * 512 * 2);
  u16* WkmT = (u16*)alloc((size_t)NG4 * 2048 * 2);   // aliased: Q/Phz/Phzp/Pgh after P0
  u16* WkyT = (u16*)alloc((size_t)NG4 * 1024 * 2);
  u16* WrT  = (u16*)alloc((size_t)NG4 * NH * 2);
  u16* W1T  = (u16*)alloc((size_t)NF * NH * 2);
  u16* W2T  = (u16*)alloc((size_t)NF * NF * 2);
  u16* W3T  = (u16*)alloc((size_t)NF * NF * 2);
  u16* W4T  = (u16*)alloc((size_t)NZ * 6144 * 2);
  u16* W56T = (u16*)alloc((size_t)1024 * NZ * 2);
  u16* W7T  = (u16*)alloc((size_t)NZ * 5120 * 2);
  u16* W89T = (u16*)alloc((size_t)1024 * NZ * 2);
  u16* hi_bf = (u16*)alloc((size_t)NB * NH * 2);
  float* bq  = (float*)alloc(2048 * 4);
  float* Gc  = (float*)alloc((size_t)NB * NG4 * 4);
  float* H4c = (float*)alloc((size_t)NB * NZ * 4);
  float* H7c = (float*)alloc((size_t)NB * NZ * 4);
  float* lam = (float*)alloc((size_t)NB * NT * 4);
  u16* hbfV = (u16*)alloc((size_t)(NT + 1) * NB * NH * 2);
  u16* zV   = (u16*)alloc((size_t)(NT + 1) * NB * NZ * 2);
  u16* yV   = (u16*)alloc((size_t)(NT + 1) * NB * NF * 2);
  u16* sbfV = (u16*)alloc((size_t)NT * NB * NH * 2);
  u16* y1V  = (u16*)alloc((size_t)NT * NB * NF * 2);
  u16* y2V  = (u16*)alloc((size_t)NT * NB * NF * 2);
  u16* hzV  = (u16*)alloc((size_t)NT * NB * NZ * 2);
  u16* hzpV = (u16*)alloc((size_t)NT * NB * NZ * 2);
  char* zero_start = wsb + off;
  unsigned* bar = (unsigned*)alloc(2048);
  size_t zero_bytes = (size_t)((wsb + off) - zero_start);

  float* out_ys   = out;
  float* out_mean = out_ys + (size_t)NB * NT * NF;
  float* out_logv = out_mean + (size_t)NB * NT * NZ;
  float* out_zs   = out_logv + (size_t)NB * NT * NZ;
  float* out_zps  = out_zs + (size_t)NB * NT * NZ;
  float* out_it   = out_zps + (size_t)NB * NT * NZ;
  float* out_te   = out_it + (size_t)NB * NT;

  hipMemsetAsync(zero_start, 0, zero_bytes, stream);   // barrier flags only

  TJobs tj{};
  const float* srcs[13] = {Wk, Wk, Wk, Wr, W1, W2, W3, W4, W5, W6, W7, W8, W9};
  u16* dsts[13] = {WkzT, WkmT, WkyT, WrT, W1T, W2T, W3T, W4T,
                   W56T, W56T + (size_t)NZ * NZ, W7T, W89T, W89T + (size_t)NZ * NZ};
  int Ns[13]   = {8192, 8192, 8192, 8192, 1024, 1024, 1024, 512, 512, 512, 512, 512, 512};
  int klos[13] = {0, 512, 2560, 0, 0, 0, 0, 0, 0, 0, 0, 0, 0};
  int klens[13]= {512, 2048, 1024, 2048, 2048, 1024, 1024, 6144, 512, 512, 5120, 512, 512};
  int cum = 0;
  for (int k = 0; k < 13; ++k) {
    tj.W[k] = srcs[k]; tj.D[k] = dsts[k]; tj.N[k] = Ns[k]; tj.klo[k] = klos[k];
    tj.ntx[k] = klens[k] / 32;
    tj.base[k] = cum;
    cum += (klens[k] / 32) * (Ns[k] / 32);
  }
  tj.base[13] = cum;
  tj.h_i = h_i; tj.hi_bf = hi_bf; tj.hi_base = cum;
  const int total_blocks = cum + (NB * NH / 4) / 256;
  setup_tr<<<dim3(total_blocks), dim3(256), 0, stream>>>(tj);

  misc_k<<<dim3(24), dim3(256), 0, stream>>>(in_t, alpha, beta, base_, tw,
                                             b5, b6, b8, b9, lam, out_it, out_te, bq);

  PArgs pa{};
  pa.WkzT = WkzT; pa.WkyT = WkyT; pa.WkmT = WkmT; pa.WrT = WrT;
  pa.W1T = W1T; pa.W2T = W2T; pa.W3T = W3T; pa.W4T = W4T;
  pa.W56T = W56T; pa.W7T = W7T; pa.W89T = W89T; pa.hi_bf = hi_bf;
  pa.bl = bl; pa.b1 = b1; pa.b2 = b2; pa.b3 = b3; pa.b4 = b4; pa.b7 = b7;
  pa.bq = bq; pa.ninf = ninf; pa.npri = npri; pa.lam = lam;
  pa.Gc = Gc; pa.H4c = H4c; pa.H7c = H7c; pa.R = (float*)WkmT;
  pa.Pgh = (u16*)((float*)WkmT + (size_t)11 * NB * 512);
  pa.hbfV = hbfV; pa.zV = zV; pa.yV = yV; pa.sbfV = sbfV;
  pa.y1V = y1V; pa.y2V = y2V; pa.hzV = hzV; pa.hzpV = hzpV;
  pa.o_ys = out_ys; pa.o_mean = out_mean; pa.o_logv = out_logv;
  pa.o_zs = out_zs; pa.o_zps = out_zps;
  pa.flags = bar; pa.rel = bar + 384;
  persist<<<dim3(NBLK), dim3(256), 0, stream>>>(pa);
}

// Round 15
// 1707.577 us; speedup vs baseline: 1.0216x; 1.0216x over previous
//
#include <hip/hip_runtime.h>
#include <stdint.h>

typedef unsigned short u16;
typedef __bf16 bf16x8 __attribute__((ext_vector_type(8)));
typedef float f32x4 __attribute__((ext_vector_type(4)));

static constexpr int NB  = 256;
static constexpr int NH  = 2048;
static constexpr int NF  = 1024;
static constexpr int NZ  = 512;
static constexpr int NT  = 16;
static constexpr int NTS = 32;
static constexpr int NG4 = 8192;
static constexpr int NBLK = 256;

// ---------- helpers ----------
__device__ __forceinline__ u16 f2bf(float f) {
  union { float f; uint32_t u; } x; x.f = f;
  uint32_t r = x.u + 0x7fffu + ((x.u >> 16) & 1u);
  return (u16)(r >> 16);
}
__device__ __forceinline__ float b2f(u16 v) {
  union { float f; uint32_t u; } c; c.u = (uint32_t)v << 16; return c.f;
}
__device__ __forceinline__ float sigm(float x) { return 1.f / (1.f + expf(-x)); }

__device__ __forceinline__ void gload16(const void* g, void* l) {
  __builtin_amdgcn_global_load_lds(
      (__attribute__((address_space(1))) void*)const_cast<void*>(g),
      (__attribute__((address_space(3))) void*)l, 16, 0, 0);
}

__device__ __forceinline__ unsigned aload(const unsigned* p) {
  return __hip_atomic_load(p, __ATOMIC_RELAXED, __HIP_MEMORY_SCOPE_AGENT);
}
__device__ __forceinline__ void astore(unsigned* p, unsigned v) {
  __hip_atomic_store(p, v, __ATOMIC_RELAXED, __HIP_MEMORY_SCOPE_AGENT);
}
__device__ __forceinline__ void t_st(float* p, float v) {
  __hip_atomic_store(p, v, __ATOMIC_RELAXED, __HIP_MEMORY_SCOPE_AGENT);
}
__device__ __forceinline__ void t_st32(uint32_t* p, uint32_t v) {
  __hip_atomic_store(p, v, __ATOMIC_RELAXED, __HIP_MEMORY_SCOPE_AGENT);
}

// vectorized cache-bypassing (sc0 sc1) ops (r8/r10/r11-proven)
__device__ __forceinline__ void tl4(const float* p, f32x4& v) {
  asm volatile("global_load_dwordx4 %0, %1, off sc0 sc1" : "=&v"(v) : "v"(p));
}
__device__ __forceinline__ void ts2(void* p, uint32_t lo, uint32_t hi) {
  uint2 d; d.x = lo; d.y = hi;
  asm volatile("global_store_dwordx2 %0, %1, off sc0 sc1" :: "v"(p), "v"(d) : "memory");
}
__device__ __forceinline__ void t_wait() {
  asm volatile("s_waitcnt vmcnt(0)" ::: "memory");
  __builtin_amdgcn_sched_barrier(0);
}

// ---------- grid barrier v3 (r7/r10/r11-proven) ----------
__device__ __forceinline__ void gsync(unsigned* flags, unsigned* rel, unsigned& epoch) {
  ++epoch;
  asm volatile("s_waitcnt vmcnt(0)" ::: "memory");
  __syncthreads();
  if (blockIdx.x == 0) {
    if (threadIdx.x > 0)
      while (aload(&flags[threadIdx.x]) < epoch) __builtin_amdgcn_s_sleep(1);
    __syncthreads();
    if (threadIdx.x == 0) astore(rel, epoch);
  } else if (threadIdx.x == 0) {
    astore(&flags[blockIdx.x], epoch);
    while (aload(rel) < epoch) __builtin_amdgcn_s_sleep(1);
  }
  __syncthreads();
}

// ---------- pipelined GEMM tile core, templated on row-fragments F ----------
template<int F>
__device__ __forceinline__ void gemm_core(const u16* __restrict__ A, const u16* __restrict__ W,
                                          int lda, int ldw, int niter, int wg,
                                          char* lds, f32x4 (&acc)[F][4]) {
  constexpr int BUF = F * 4096 + 4096;
  const int tid = threadIdx.x, lane = tid & 63, wave = tid >> 6;
  const int srow = lane >> 2;
  const int schunk = (((lane & 3) ^ ((lane >> 3) & 3)) << 3);
  const u16* ga = A + (size_t)(wave * (F * 16) + srow) * lda + schunk;
  const u16* gw = W + (size_t)(wave * wg + srow) * ldw + schunk;
  const size_t astep = (size_t)16 * lda;
  auto STAGE = [&](int idx) {
    const int koff = idx << 5;
    char* base = lds + (idx % 3) * BUF;
    char* ad = base + wave * (F * 1024);
#pragma unroll
    for (int k = 0; k < F; ++k) gload16(ga + koff + k * astep, ad + k * 1024);
    gload16(gw + koff, base + F * 4096 + wave * 1024);
  };
  int rA[F], rW[4];
  const int b15 = lane & 15, h4 = lane >> 4, rx = (b15 >> 1) & 3;
#pragma unroll
  for (int f = 0; f < F; ++f) rA[f] = (wave * (F * 16) + f * 16 + b15) * 64 + ((h4 ^ rx) << 4);
#pragma unroll
  for (int q = 0; q < 4; ++q) rW[q] = F * 4096 + (q * 16 + b15) * 64 + ((h4 ^ rx) << 4);

  const int npro = niter < 3 ? niter : 3;
  for (int j = 0; j < npro; ++j) STAGE(j);
  for (int i = 0; i < niter; ++i) {
    const int ahead = niter - 1 - i;
    if constexpr (F == 4) {
      if (ahead >= 2)      asm volatile("s_waitcnt vmcnt(10)" ::: "memory");
      else if (ahead == 1) asm volatile("s_waitcnt vmcnt(5)" ::: "memory");
      else                 asm volatile("s_waitcnt vmcnt(0)" ::: "memory");
    } else if constexpr (F == 2) {
      if (ahead >= 2)      asm volatile("s_waitcnt vmcnt(6)" ::: "memory");
      else if (ahead == 1) asm volatile("s_waitcnt vmcnt(3)" ::: "memory");
      else                 asm volatile("s_waitcnt vmcnt(0)" ::: "memory");
    } else {
      if (ahead >= 2)      asm volatile("s_waitcnt vmcnt(4)" ::: "memory");
      else if (ahead == 1) asm volatile("s_waitcnt vmcnt(2)" ::: "memory");
      else                 asm volatile("s_waitcnt vmcnt(0)" ::: "memory");
    }
    __builtin_amdgcn_sched_barrier(0);
    asm volatile("s_barrier" ::: "memory");
    __builtin_amdgcn_sched_barrier(0);
    const char* base = lds + (i % 3) * BUF;
    bf16x8 av[F], bv[4];
#pragma unroll
    for (int f = 0; f < F; ++f) av[f] = *(const bf16x8*)(base + rA[f]);
#pragma unroll
    for (int q = 0; q < 4; ++q) bv[q] = *(const bf16x8*)(base + rW[q]);
    asm volatile("s_waitcnt lgkmcnt(0)" ::: "memory");
    __builtin_amdgcn_sched_barrier(0);
    asm volatile("s_barrier" ::: "memory");
    __builtin_amdgcn_sched_barrier(0);
    if (i + 3 < niter) STAGE(i + 3);
#pragma unroll
    for (int f = 0; f < F; ++f)
#pragma unroll
      for (int q = 0; q < 4; ++q)
        acc[f][q] = __builtin_amdgcn_mfma_f32_16x16x32_bf16(av[f], bv[q], acc[f][q], 0, 0, 0);
  }
}

// ---------- LDS-staged vectorized tile flushes ----------
__device__ __forceinline__ void flush_u16(const char* tb, u16* dst, int rs, int m0, int n0) {
  __syncthreads();
  const int tid = threadIdx.x, row = tid >> 2, qt = tid & 3;
  const uint2* s = (const uint2*)(tb + row * 128 + qt * 32);
  u16* d = dst + (size_t)(m0 + row) * rs + n0 + qt * 16;
  ts2(d, s[0].x, s[0].y);
  ts2(d + 4, s[1].x, s[1].y);
  ts2(d + 8, s[2].x, s[2].y);
  ts2(d + 12, s[3].x, s[3].y);
}
__device__ __forceinline__ void flush_f32(const char* tb, float* dst, int rs, int m0, int n0) {
  __syncthreads();
  const int tid = threadIdx.x, row = tid >> 2, qt = tid & 3;
  const uint2* s = (const uint2*)(tb + row * 256 + qt * 64);
  float* d = dst + (size_t)(m0 + row) * rs + n0 + qt * 16;
#pragma unroll
  for (int i = 0; i < 8; ++i) ts2(d + i * 2, s[i].x, s[i].y);
}

// P0-only: write bias-added 256-row tile via scalar through-stores
__device__ __forceinline__ void wbias(float* of, const float* bias, int Nn, int n0,
                                      const f32x4 (&acc)[4][4]) {
  const int tid = threadIdx.x, lane = tid & 63, wave = tid >> 6;
  const int b15 = lane & 15, h4 = lane >> 4;
#pragma unroll
  for (int q = 0; q < 4; ++q) {
    const int n = n0 + q * 16 + b15;
    const float bb = bias[n];
#pragma unroll
    for (int f = 0; f < 4; ++f) {
      const int m = wave * 64 + f * 16 + h4 * 4;
#pragma unroll
      for (int r = 0; r < 4; ++r) t_st(&of[(size_t)(m + r) * Nn + n], acc[f][q][r] + bb);
    }
  }
}

// ---------- batched setup ----------
struct TJobs {
  const float* W[13]; u16* D[13];
  int N[13], klo[13], ntx[13], base[14];
  const float* h_i; u16* hi_bf; int hi_base;
};
__global__ __launch_bounds__(256) void setup_tr(TJobs j) {
  const int bid = blockIdx.x, t = threadIdx.x;
  if (bid >= j.hi_base) {
    int i = ((bid - j.hi_base) * 256 + t) * 4;
    float4 v = *(const float4*)(j.h_i + i);
    ushort4 o; o.x = f2bf(v.x); o.y = f2bf(v.y); o.z = f2bf(v.z); o.w = f2bf(v.w);
    *(ushort4*)(j.hi_bf + i) = o;
    return;
  }
  int k = 0;
  while (bid >= j.base[k + 1]) ++k;
  const int tix = bid - j.base[k];
  const int ntx = j.ntx[k];
  const int kk0 = (tix % ntx) * 32, n0 = (tix / ntx) * 32;
  const int N = j.N[k], k_lo = j.klo[k], k_len = ntx * 32;
  const float* W = j.W[k];
  u16* WT = j.D[k];
  __shared__ float tile[32][33];
  const int r = t >> 3, cg = t & 7;
  const float4 v = *(const float4*)(W + (size_t)(k_lo + kk0 + r) * N + n0 + cg * 4);
  tile[r][cg * 4 + 0] = v.x; tile[r][cg * 4 + 1] = v.y;
  tile[r][cg * 4 + 2] = v.z; tile[r][cg * 4 + 3] = v.w;
  __syncthreads();
  ushort4 o;
  o.x = f2bf(tile[cg * 4 + 0][r]);
  o.y = f2bf(tile[cg * 4 + 1][r]);
  o.z = f2bf(tile[cg * 4 + 2][r]);
  o.w = f2bf(tile[cg * 4 + 3][r]);
  *(ushort4*)(WT + (size_t)(n0 + r) * k_len + kk0 + cg * 4) = o;
}

// ---------- misc ----------
__global__ __launch_bounds__(256) void misc_k(const float* __restrict__ input_t,
                                              const float* alpha, const float* beta,
                                              const float* base_, const float* tw,
                                              const float* b5, const float* b6,
                                              const float* b8, const float* b9,
                                              float* __restrict__ lam_buf,
                                              float* __restrict__ out_it,
                                              float* __restrict__ out_te,
                                              float* __restrict__ bq) {
  const int bid = blockIdx.x, tid = threadIdx.x;
  if (bid < 16) {
    int i = bid * 256 + tid;
    int b = i >> 4, jj = i & 15;
    const float* row = input_t + b * NTS;
    float cur = row[16 + jj];
    float trig = 0.f;
    int lim = 16 + jj;
    for (int s = 0; s < lim; ++s) trig += expf(row[s] - cur);
    float lam = base_[0] + alpha[0] * beta[0] * trig;
    float x = lam * (2048.f * tw[0]);
    float dt = (x > 15.f) ? x : log1pf(expf(x));
    lam_buf[b * NT + jj] = lam;
    out_it[jj * NB + b] = cur;
    out_te[jj * NB + b] = cur + dt;
  } else {
    int i = (bid - 16) * 256 + tid;
    bq[i] = (i < 512) ? b5[i] : (i < 1024) ? b6[i - 512]
          : (i < 1536) ? b8[i - 1024] : b9[i - 1536];
  }
}

// ---------- the persistent decoder kernel ----------
struct PArgs {
  const u16 *WkzT, *WkyT, *WkmT, *WrT, *W1T, *W2T, *W3T, *W4T, *W56T, *W7T, *W89T, *hi_bf;
  const float *bl, *b1, *b2, *b3, *b4, *b7, *bq, *ninf, *npri, *lam;
  float *Gc, *H4c, *H7c, *R;
  u16 *Pgh;                      // [2][256 tiles][128*64] bf16 Wr partials
  u16 *hbfV, *zV, *yV, *sbfV, *y1V, *y2V, *hzV, *hzpV;
  float *o_ys, *o_mean, *o_logv, *o_zs, *o_zps;
  unsigned *flags, *rel;
};

__global__ __launch_bounds__(256) void persist(PArgs a) {
  __shared__ __attribute__((aligned(16))) char lds[3 * 20480];
  const int bid = blockIdx.x, tid = threadIdx.x;
  const int lane = tid & 63, wave = tid >> 6, b15 = lane & 15, h4 = lane >> 4;
  unsigned epoch = 0;
  float* Q    = a.R;
  float* Phz  = a.R + (size_t)4 * NB * 512;       // planes 0..2 used
  float* Phzp = a.R + (size_t)8 * NB * 512;       // planes 0..2
  char* tb = lds + 24576;

  const int g_mh = bid >> 7;
  const int g_c0 = (bid & 127) * 16;
  float cR[2][4];
#pragma unroll
  for (int f = 0; f < 2; ++f)
#pragma unroll
    for (int r = 0; r < 4; ++r) cR[f][r] = 0.f;

  // ---- P0 (r10-r13 verbatim)
  {
    if (bid < 144) {
      f32x4 acc[4][4] = {};
      if (bid < 128) {
        const int n0 = bid * 64;
        gemm_core<4>(a.hi_bf, a.WkmT + (size_t)n0 * 2048, 2048, 2048, 64, 16, lds, acc);
        wbias(a.Gc, a.bl, NG4, n0, acc);
      } else if (bid < 136) {
        const int n0 = (bid - 128) * 64;
        gemm_core<4>(a.hi_bf, a.W4T + (size_t)n0 * 6144, 2048, 6144, 64, 16, lds, acc);
        wbias(a.H4c, a.b4, NZ, n0, acc);
      } else {
        const int n0 = (bid - 136) * 64;
        gemm_core<4>(a.hi_bf, a.W7T + (size_t)n0 * 5120, 2048, 5120, 64, 16, lds, acc);
        wbias(a.H7c, a.b7, NZ, n0, acc);
      }
    } else {
      const int zt = (bid - 144) * 256 + tid, nthr = 112 * 256;
      for (int w = zt; w < NB * NH / 2; w += nthr) t_st32((uint32_t*)a.hbfV + w, 0u);
      for (int w = zt; w < NB * NZ / 2; w += nthr) t_st32((uint32_t*)a.zV + w, 0u);
      for (int w = zt; w < NB * NF / 2; w += nthr) t_st32((uint32_t*)a.yV + w, 0u);
    }
    gsync(a.flags, a.rel, epoch);
  }

  float GcR[2][4][4];
#pragma unroll
  for (int f = 0; f < 2; ++f)
#pragma unroll
    for (int q = 0; q < 4; ++q)
#pragma unroll
      for (int r = 0; r < 4; ++r) {
        const int m = g_mh * 128 + wave * 32 + f * 16 + h4 * 4 + r;
        GcR[f][q][r] = a.Gc[(size_t)m * NG4 + q * 2048 + g_c0 + b15];
      }

  for (int t = 0; t < NT; ++t) {
    u16* hbf_n = a.hbfV + (size_t)(t + 1) * NB * NH;
    const u16* z_t = a.zV + (size_t)t * NB * NZ;
    u16* z_n = a.zV + (size_t)(t + 1) * NB * NZ;
    const u16* yp = a.yV + (size_t)t * NB * NF;
    u16* yc = a.yV + (size_t)(t + 1) * NB * NF;
    u16* sbf = a.sbfV + (size_t)t * NB * NH;
    u16* y1bf = a.y1V + (size_t)t * NB * NF;
    u16* y2bf = a.y2V + (size_t)t * NB * NF;
    u16* hzbf = a.hzV + (size_t)t * NB * NZ;
    u16* hzpbf = a.hzpV + (size_t)t * NB * NZ;

    // Wr-precompute job for step t+1 (runs on idle blocks in PH3/PH4/PH5)
    auto wr_job = [&](int j) {
      if (t >= NT - 1) return;
      const int tile = j & 255, half = j >> 8;
      const int mh = tile >> 7, c0 = (tile & 127) * 16;
      f32x4 jac[2][4] = {};
      gemm_core<2>(hbf_n + (size_t)mh * 128 * 2048 + half * 1024,
                   a.WrT + (size_t)c0 * 2048 + half * 1024,
                   2048, 2048, 32, 2048, lds, jac);
      u16* tlj = (u16*)(lds + 36864);
#pragma unroll
      for (int f = 0; f < 2; ++f)
#pragma unroll
        for (int q = 0; q < 4; ++q)
#pragma unroll
          for (int r = 0; r < 4; ++r)
            tlj[(wave * 32 + f * 16 + h4 * 4 + r) * 64 + q * 16 + b15] = f2bf(jac[f][q][r]);
      __syncthreads();
      u16* dst = a.Pgh + ((size_t)half * 256 + tile) * 8192;
      const int row = tid >> 1, co = (tid & 1) * 32;
      const uint2* s = (const uint2*)(lds + 36864 + row * 128 + co * 2);
      u16* d = dst + row * 64 + co;
#pragma unroll
      for (int i = 0; i < 8; ++i) ts2(d + i * 4, s[i].x, s[i].y);
    };

    // ---- PH1: gates (z,yp) + precomputed Wr tiles + LSTM cell (256 blocks)
    {
      f32x4 acc[2][4] = {};
      gemm_core<2>(z_t + (size_t)g_mh * 128 * 512, a.WkzT + (size_t)g_c0 * 512,
                   512, 512, 16, 2048, lds, acc);
      gemm_core<2>(yp + (size_t)g_mh * 128 * 1024, a.WkyT + (size_t)g_c0 * 1024,
                   1024, 1024, 32, 2048, lds, acc);
      __syncthreads();
      if (t > 0) {
        // load this block's 2 Wr half-tiles (cache-bypassed) into LDS
        const float* t0 = (const float*)(a.Pgh + (size_t)bid * 8192);
        const float* t1 = (const float*)(a.Pgh + (size_t)(256 + bid) * 8192);
        f32x4 v0[4], v1[4];
#pragma unroll
        for (int i = 0; i < 4; ++i) tl4(t0 + tid * 16 + i * 4, v0[i]);
#pragma unroll
        for (int i = 0; i < 4; ++i) tl4(t1 + tid * 16 + i * 4, v1[i]);
        t_wait();
        f32x4* l0 = (f32x4*)(lds + tid * 64);
        f32x4* l1 = (f32x4*)(lds + 16384 + tid * 64);
#pragma unroll
        for (int i = 0; i < 4; ++i) { l0[i] = v0[i]; l1[i] = v1[i]; }
      }
      __syncthreads();
      const u16* T0 = (const u16*)lds;
      const u16* T1 = (const u16*)(lds + 16384);
      u16* tlh = (u16*)(lds + 36864);
      u16* tls = (u16*)(lds + 36864 + 4096);
#pragma unroll
      for (int f = 0; f < 2; ++f)
#pragma unroll
        for (int r = 0; r < 4; ++r) {
          const int ml = wave * 32 + f * 16 + h4 * 4 + r;
          const int m = g_mh * 128 + ml;
          float g4[4];
#pragma unroll
          for (int q = 0; q < 4; ++q) {
            float v = acc[f][q][r] + GcR[f][q][r];
            if (t > 0)
              v += b2f(T0[ml * 64 + q * 16 + b15]) + b2f(T1[ml * 64 + q * 16 + b15]);
            g4[q] = v;
          }
          const float cn = sigm(g4[1]) * cR[f][r] + sigm(g4[0]) * tanhf(g4[2]);
          const float hn = sigm(g4[3]) * tanhf(cn);
          cR[f][r] = a.lam[m * NT + t] * cn;
          tlh[ml * 16 + b15] = f2bf(hn);
          tls[ml * 16 + b15] = f2bf(cn);
        }
      __syncthreads();
      {
        const int row = tid >> 1, half = tid & 1;
        const char* srch = lds + 36864 + row * 32 + half * 16;
        uint2 u0 = *(const uint2*)srch;
        uint2 u1 = *(const uint2*)(srch + 8);
        u16* dh = hbf_n + (size_t)(g_mh * 128 + row) * NH + g_c0 + half * 8;
        ts2(dh, u0.x, u0.y);
        ts2(dh + 4, u1.x, u1.y);
        const char* srcs = lds + 36864 + 4096 + row * 32 + half * 16;
        uint2 s0 = *(const uint2*)srcs;
        uint2 s1 = *(const uint2*)(srcs + 8);
        u16* dsp = sbf + (size_t)(g_mh * 128 + row) * NH + g_c0 + half * 8;
        ts2(dsp, s0.x, s0.y);
        ts2(dsp + 4, s1.x, s1.y);
      }
      gsync(a.flags, a.rel, epoch);
    }

    // ---- PH2 (256 blocks): y1 ∥ hz-sbf(k2) ∥ hz-yp ∥ hzp-sbf(k2) ∥ hzp-yp (r13-verbatim)
    {
      if (bid < 64) {
        const int mt = bid >> 4, nt = bid & 15, m0 = mt * 64, n0 = nt * 64;
        f32x4 acc[1][4] = {};
        gemm_core<1>(hbf_n + (size_t)m0 * 2048, a.W1T + (size_t)n0 * 2048,
                     2048, 2048, 64, 16, lds, acc);
        u16* tl = (u16*)tb;
#pragma unroll
        for (int q = 0; q < 4; ++q) {
          const float bb = a.b1[n0 + q * 16 + b15];
#pragma unroll
          for (int r = 0; r < 4; ++r) {
            const int ml = wave * 16 + h4 * 4 + r;
            tl[ml * 64 + q * 16 + b15] = f2bf(fmaxf(acc[0][q][r] + bb, 0.f));
          }
        }
        flush_u16(tb, y1bf, NF, m0, n0);
      } else if (bid < 128) {
        const int s = bid - 64, mt = s >> 4, rest = s & 15, nt = rest & 7, k = rest >> 3;
        const int m0 = mt * 64, n0 = nt * 64;
        f32x4 acc[1][4] = {};
        gemm_core<1>(sbf + (size_t)m0 * 2048 + k * 1024,
                     a.W4T + 2048 + (size_t)n0 * 6144 + k * 1024,
                     2048, 6144, 32, 16, lds, acc);
        float* tf = (float*)tb;
#pragma unroll
        for (int q = 0; q < 4; ++q)
#pragma unroll
          for (int r = 0; r < 4; ++r)
            tf[(wave * 16 + h4 * 4 + r) * 64 + q * 16 + b15] = acc[0][q][r];
        flush_f32(tb, Phz + (size_t)k * NB * 512, 512, m0, n0);
      } else if (bid < 160) {
        const int s = bid - 128, mt = s >> 3, nt = s & 7, m0 = mt * 64, n0 = nt * 64;
        f32x4 acc[1][4] = {};
        gemm_core<1>(yp + (size_t)m0 * 1024, a.W4T + 5120 + (size_t)n0 * 6144,
                     1024, 6144, 32, 16, lds, acc);
        float* tf = (float*)tb;
#pragma unroll
        for (int q = 0; q < 4; ++q)
#pragma unroll
          for (int r = 0; r < 4; ++r)
            tf[(wave * 16 + h4 * 4 + r) * 64 + q * 16 + b15] = acc[0][q][r];
        flush_f32(tb, Phz + (size_t)2 * NB * 512, 512, m0, n0);
      } else if (bid < 224) {
        const int s = bid - 160, mt = s >> 4, rest = s & 15, nt = rest & 7, k = rest >> 3;
        const int m0 = mt * 64, n0 = nt * 64;
        f32x4 acc[1][4] = {};
        gemm_core<1>(sbf + (size_t)m0 * 2048 + k * 1024,
                     a.W7T + 2048 + (size_t)n0 * 5120 + k * 1024,
                     2048, 5120, 32, 16, lds, acc);
        float* tf = (float*)tb;
#pragma unroll
        for (int q = 0; q < 4; ++q)
#pragma unroll
          for (int r = 0; r < 4; ++r)
            tf[(wave * 16 + h4 * 4 + r) * 64 + q * 16 + b15] = acc[0][q][r];
        flush_f32(tb, Phzp + (size_t)k * NB * 512, 512, m0, n0);
      } else {
        const int s = bid - 224, mt = s >> 3, nt = s & 7, m0 = mt * 64, n0 = nt * 64;
        f32x4 acc[1][4] = {};
        gemm_core<1>(yp + (size_t)m0 * 1024, a.W7T + 4096 + (size_t)n0 * 5120,
                     1024, 5120, 32, 16, lds, acc);
        float* tf = (float*)tb;
#pragma unroll
        for (int q = 0; q < 4; ++q)
#pragma unroll
          for (int r = 0; r < 4; ++r)
            tf[(wave * 16 + h4 * 4 + r) * 64 + q * 16 + b15] = acc[0][q][r];
        flush_f32(tb, Phzp + (size_t)2 * NB * 512, 512, m0, n0);
      }
      gsync(a.flags, a.rel, epoch);
    }

    // ---- PH3: y2 (0-63) ∥ hzp-comb (64-95) ∥ Wr jobs 0-159 (96-255)
    {
      if (bid < 64) {
        const int mt = bid >> 4, nt = bid & 15, m0 = mt * 64, n0 = nt * 64;
        f32x4 acc[1][4] = {};
        gemm_core<1>(y1bf + (size_t)m0 * 1024, a.W2T + (size_t)n0 * 1024,
                     1024, 1024, 32, 16, lds, acc);
        u16* tl = (u16*)tb;
#pragma unroll
        for (int q = 0; q < 4; ++q) {
          const float bb = a.b2[n0 + q * 16 + b15];
#pragma unroll
          for (int r = 0; r < 4; ++r) {
            const int ml = wave * 16 + h4 * 4 + r;
            tl[ml * 64 + q * 16 + b15] = f2bf(fmaxf(acc[0][q][r] + bb, 0.f));
          }
        }
        flush_u16(tb, y2bf, NF, m0, n0);
      } else if (bid < 96) {
        const int cb = bid - 64;
        for (int p = 0; p < 4; ++p) {
          const int idx = ((p * 32 + cb) * 256 + tid) * 4;
          f32x4 v0, v1, v2;
          tl4(Phzp + idx, v0);
          tl4(Phzp + (size_t)NB * 512 + idx, v1);
          tl4(Phzp + (size_t)2 * NB * 512 + idx, v2);
          f32x4 c0 = *(const f32x4*)(a.H7c + idx);
          t_wait();
          f32x4 v = v0 + v1 + v2 + c0;
          u16 o[4];
#pragma unroll
          for (int r = 0; r < 4; ++r) o[r] = f2bf(fmaxf(v[r], 0.f));
          ts2(hzpbf + idx, (uint32_t)o[0] | ((uint32_t)o[1] << 16),
                           (uint32_t)o[2] | ((uint32_t)o[3] << 16));
        }
      } else {
        wr_job(bid - 96);
      }
      gsync(a.flags, a.rel, epoch);
    }

    // ---- PH4: y3 -> yc + o_ys (0-63) ∥ heads-pri -> Q (64-127) ∥ Wr jobs 160-287
    {
      if (bid < 64) {
        const int mt = bid >> 4, nt = bid & 15, m0 = mt * 64, n0 = nt * 64;
        f32x4 acc[1][4] = {};
        gemm_core<1>(y2bf + (size_t)m0 * 1024, a.W3T + (size_t)n0 * 1024,
                     1024, 1024, 32, 16, lds, acc);
        u16* tl = (u16*)tb;
#pragma unroll
        for (int q = 0; q < 4; ++q) {
          const int n = n0 + q * 16 + b15;
          const float bb = a.b3[n];
#pragma unroll
          for (int r = 0; r < 4; ++r) {
            const int ml = wave * 16 + h4 * 4 + r;
            const float v = fmaxf(acc[0][q][r] + bb, 0.f);
            tl[ml * 64 + q * 16 + b15] = f2bf(v);
            a.o_ys[((size_t)(m0 + ml) * NT + t) * NF + n] = v;
          }
        }
        flush_u16(tb, yc, NF, m0, n0);
      } else if (bid < 128) {
        const int s = bid - 64, mt = s >> 4, nt = s & 15, m0 = mt * 64, n0 = nt * 64;
        f32x4 acc[1][4] = {};
        gemm_core<1>(hzpbf + (size_t)m0 * 512, a.W89T + (size_t)n0 * 512,
                     512, 512, 16, 16, lds, acc);
        float* tf = (float*)tb;
#pragma unroll
        for (int q = 0; q < 4; ++q) {
          const float bb = a.bq[1024 + n0 + q * 16 + b15];
#pragma unroll
          for (int r = 0; r < 4; ++r)
            tf[(wave * 16 + h4 * 4 + r) * 64 + q * 16 + b15] = fmaxf(acc[0][q][r] + bb, 0.f);
        }
        const int plane = 2 + (n0 >> 9), col0 = n0 & 511;
        flush_f32(tb, Q + (size_t)plane * NB * 512, 512, m0, col0);
      } else {
        wr_job(160 + bid - 128);
      }
      gsync(a.flags, a.rel, epoch);
    }

    // ---- PH5: hzB (yc@W4b) + FUSED hz-comb -> hzbf (0-31, vectorized) ∥ Wr jobs 288-511
    {
      if (bid < 32) {
        const int mt = bid >> 3, nt = bid & 7, m0 = mt * 64, n0 = nt * 64;
        f32x4 acc[1][4] = {};
        gemm_core<1>(yc + (size_t)m0 * 1024, a.W4T + 4096 + (size_t)n0 * 6144,
                     1024, 6144, 32, 16, lds, acc);
        float* tf = (float*)tb;
#pragma unroll
        for (int q = 0; q < 4; ++q)
#pragma unroll
          for (int r = 0; r < 4; ++r)
            tf[(wave * 16 + h4 * 4 + r) * 64 + q * 16 + b15] = acc[0][q][r];
        __syncthreads();
        const int row = tid >> 2, qt = tid & 3;
        const size_t base = (size_t)(m0 + row) * 512 + n0 + qt * 16;
        f32x4 p0[4], p1[4], p2[4];
#pragma unroll
        for (int i = 0; i < 4; ++i) {
          tl4(Phz + base + i * 4, p0[i]);
          tl4(Phz + (size_t)NB * 512 + base + i * 4, p1[i]);
          tl4(Phz + (size_t)2 * NB * 512 + base + i * 4, p2[i]);
        }
        t_wait();
#pragma unroll
        for (int i = 0; i < 4; ++i) {
          f32x4 v = *(const f32x4*)(tf + row * 64 + qt * 16 + i * 4)
                  + p0[i] + p1[i] + p2[i]
                  + *(const f32x4*)(a.H4c + base + i * 4);
          u16 o[4];
#pragma unroll
          for (int r = 0; r < 4; ++r) o[r] = f2bf(fmaxf(v[r], 0.f));
          ts2(hzbf + base + i * 4, (uint32_t)o[0] | ((uint32_t)o[1] << 16),
                                   (uint32_t)o[2] | ((uint32_t)o[3] << 16));
        }
      } else {
        wr_job(288 + bid - 32);
      }
      gsync(a.flags, a.rel, epoch);
    }

    // ---- PH6: heads-inf -> Q planes 0/1 (64 blocks)
    {
      if (bid < 64) {
        const int mt = bid >> 4, nt = bid & 15, m0 = mt * 64, n0 = nt * 64;
        f32x4 acc[1][4] = {};
        gemm_core<1>(hzbf + (size_t)m0 * 512, a.W56T + (size_t)n0 * 512,
                     512, 512, 16, 16, lds, acc);
        float* tf = (float*)tb;
#pragma unroll
        for (int q = 0; q < 4; ++q) {
          const float bb = a.bq[n0 + q * 16 + b15];
#pragma unroll
          for (int r = 0; r < 4; ++r)
            tf[(wave * 16 + h4 * 4 + r) * 64 + q * 16 + b15] = fmaxf(acc[0][q][r] + bb, 0.f);
        }
        const int plane = n0 >> 9, col0 = n0 & 511;
        flush_f32(tb, Q + (size_t)plane * NB * 512, 512, m0, col0);
      }
      gsync(a.flags, a.rel, epoch);
    }

    // ---- PH7: sample z/zp (128 blocks) — r13-verbatim
    {
      if (bid < 128) {
        const int g2 = bid * 256 + tid;
        const int i = g2 * 4, m = i >> 9, jj = i & 511;
        const float* qb = Q + (size_t)m * 512 + jj;
        f32x4 mean, logv, mpv, lpv;
        tl4(qb, mean);
        tl4(qb + (size_t)NB * 512, logv);
        tl4(qb + (size_t)2 * NB * 512, mpv);
        tl4(qb + (size_t)3 * NB * 512, lpv);
        f32x4 nI = *(const f32x4*)(a.ninf + (size_t)t * NB * NZ + i);
        f32x4 nP = *(const f32x4*)(a.npri + (size_t)t * NB * NZ + i);
        t_wait();
        f32x4 z, zp;
        u16 zq[4];
#pragma unroll
        for (int r = 0; r < 4; ++r) {
          z[r] = fmaf(nI[r], sqrtf(expf(logv[r])), mean[r]);
          zp[r] = fmaf(nP[r], sqrtf(expf(lpv[r])), mpv[r]);
          zq[r] = f2bf(z[r]);
        }
        const size_t oo = ((size_t)m * NT + t) * NZ + jj;
        *(f32x4*)(a.o_mean + oo) = mean;
        *(f32x4*)(a.o_logv + oo) = logv;
        *(f32x4*)(a.o_zs + oo) = z;
        *(f32x4*)(a.o_zps + oo) = zp;
        ts2(z_n + i, (uint32_t)zq[0] | ((uint32_t)zq[1] << 16),
                     (uint32_t)zq[2] | ((uint32_t)zq[3] << 16));
      }
      gsync(a.flags, a.rel, epoch);
    }
  }
}

// ---------- launcher ----------
extern "C" void kernel_launch(void* const* d_in, const int* in_sizes, int n_in,
                              void* d_out, int out_size, void* d_ws, size_t ws_size,
                              hipStream_t stream) {
  const float* h_i  = (const float*)d_in[0];
  const float* in_t = (const float*)d_in[1];
  const float* Wk   = (const float*)d_in[2];
  const float* Wr   = (const float*)d_in[3];
  const float* bl   = (const float*)d_in[4];
  const float* W1 = (const float*)d_in[5];  const float* b1 = (const float*)d_in[6];
  const float* W2 = (const float*)d_in[7];  const float* b2 = (const float*)d_in[8];
  const float* W3 = (const float*)d_in[9];  const float* b3 = (const float*)d_in[10];
  const float* W4 = (const float*)d_in[11]; const float* b4 = (const float*)d_in[12];
  const float* W5 = (const float*)d_in[13]; const float* b5 = (const float*)d_in[14];
  const float* W6 = (const float*)d_in[15]; const float* b6 = (const float*)d_in[16];
  const float* W7 = (const float*)d_in[17]; const float* b7 = (const float*)d_in[18];
  const float* W8 = (const float*)d_in[19]; const float* b8 = (const float*)d_in[20];
  const float* W9 = (const float*)d_in[21]; const float* b9 = (const float*)d_in[22];
  const float* alpha = (const float*)d_in[23];
  const float* beta  = (const float*)d_in[24];
  const float* base_ = (const float*)d_in[25];
  const float* tw    = (const float*)d_in[26];
  const float* ninf  = (const float*)d_in[27];
  const float* npri  = (const float*)d_in[28];
  float* out = (float*)d_out;
  (void)in_sizes; (void)n_in; (void)out_size; (void)ws_size;

  char* wsb = (char*)d_ws;
  size_t off = 0;
  auto alloc = [&](size_t bytes) -> void* {
    void* p = wsb + off;
    off += (bytes + 255) & ~(size_t)255;
    return p;
  };
  u16* WkzT = (u16*)alloc((size_t)NG4 * 512 * 2);
  u16* WkmT = (u16*)alloc((size_t)NG4 * 2048 * 2);   // aliased: Q/Phz/Phzp/Pgh after P0
  u16* WkyT = (u16*)alloc((size_t)NG4 * 1024 * 2);
  u16* WrT  = (u16*)alloc((size_t)NG4 * NH * 2);
  u16* W1T  = (u16*)alloc((size_t)NF * NH * 2);
  u16* W2T  = (u16*)alloc((size_t)NF * NF * 2);
  u16* W3T  = (u16*)alloc((size_t)NF * NF * 2);
  u16* W4T  = (u16*)alloc((size_t)NZ * 6144 * 2);
  u16* W56T = (u16*)alloc((size_t)1024 * NZ * 2);
  u16* W7T  = (u16*)alloc((size_t)NZ * 5120 * 2);
  u16* W89T = (u16*)alloc((size_t)1024 * NZ * 2);
  u16* hi_bf = (u16*)alloc((size_t)NB * NH * 2);
  float* bq  = (float*)alloc(2048 * 4);
  float* Gc  = (float*)alloc((size_t)NB * NG4 * 4);
  float* H4c = (float*)alloc((size_t)NB * NZ * 4);
  float* H7c = (float*)alloc((size_t)NB * NZ * 4);
  float* lam = (float*)alloc((size_t)NB * NT * 4);
  u16* hbfV = (u16*)alloc((size_t)(NT + 1) * NB * NH * 2);
  u16* zV   = (u16*)alloc((size_t)(NT + 1) * NB * NZ * 2);
  u16* yV   = (u16*)alloc((size_t)(NT + 1) * NB * NF * 2);
  u16* sbfV = (u16*)alloc((size_t)NT * NB * NH * 2);
  u16* y1V  = (u16*)alloc((size_t)NT * NB * NF * 2);
  u16* y2V  = (u16*)alloc((size_t)NT * NB * NF * 2);
  u16* hzV  = (u16*)alloc((size_t)NT * NB * NZ * 2);
  u16* hzpV = (u16*)alloc((size_t)NT * NB * NZ * 2);
  char* zero_start = wsb + off;
  unsigned* bar = (unsigned*)alloc(2048);
  size_t zero_bytes = (size_t)((wsb + off) - zero_start);

  float* out_ys   = out;
  float* out_mean = out_ys + (size_t)NB * NT * NF;
  float* out_logv = out_mean + (size_t)NB * NT * NZ;
  float* out_zs   = out_logv + (size_t)NB * NT * NZ;
  float* out_zps  = out_zs + (size_t)NB * NT * NZ;
  float* out_it   = out_zps + (size_t)NB * NT * NZ;
  float* out_te   = out_it + (size_t)NB * NT;

  hipMemsetAsync(zero_start, 0, zero_bytes, stream);   // barrier flags only

  TJobs tj{};
  const float* srcs[13] = {Wk, Wk, Wk, Wr, W1, W2, W3, W4, W5, W6, W7, W8, W9};
  u16* dsts[13] = {WkzT, WkmT, WkyT, WrT, W1T, W2T, W3T, W4T,
                   W56T, W56T + (size_t)NZ * NZ, W7T, W89T, W89T + (size_t)NZ * NZ};
  int Ns[13]   = {8192, 8192, 8192, 8192, 1024, 1024, 1024, 512, 512, 512, 512, 512, 512};
  int klos[13] = {0, 512, 2560, 0, 0, 0, 0, 0, 0, 0, 0, 0, 0};
  int klens[13]= {512, 2048, 1024, 2048, 2048, 1024, 1024, 6144, 512, 512, 5120, 512, 512};
  int cum = 0;
  for (int k = 0; k < 13; ++k) {
    tj.W[k] = srcs[k]; tj.D[k] = dsts[k]; tj.N[k] = Ns[k]; tj.klo[k] = klos[k];
    tj.ntx[k] = klens[k] / 32;
    tj.base[k] = cum;
    cum += (klens[k] / 32) * (Ns[k] / 32);
  }
  tj.base[13] = cum;
  tj.h_i = h_i; tj.hi_bf = hi_bf; tj.hi_base = cum;
  const int total_blocks = cum + (NB * NH / 4) / 256;
  setup_tr<<<dim3(total_blocks), dim3(256), 0, stream>>>(tj);

  misc_k<<<dim3(24), dim3(256), 0, stream>>>(in_t, alpha, beta, base_, tw,
                                             b5, b6, b8, b9, lam, out_it, out_te, bq);

  PArgs pa{};
  pa.WkzT = WkzT; pa.WkyT = WkyT; pa.WkmT = WkmT; pa.WrT = WrT;
  pa.W1T = W1T; pa.W2T = W2T; pa.W3T = W3T; pa.W4T = W4T;
  pa.W56T = W56T; pa.W7T = W7T; pa.W89T = W89T; pa.hi_bf = hi_bf;
  pa.bl = bl; pa.b1 = b1; pa.b2 = b2; pa.b3 = b3; pa.b4 = b4; pa.b7 = b7;
  pa.bq = bq; pa.ninf = ninf; pa.npri = npri; pa.lam = lam;
  pa.Gc = Gc; pa.H4c = H4c; pa.H7c = H7c; pa.R = (float*)WkmT;
  pa.Pgh = (u16*)((float*)WkmT + (size_t)11 * NB * 512);
  pa.hbfV = hbfV; pa.zV = zV; pa.yV = yV; pa.sbfV = sbfV;
  pa.y1V = y1V; pa.y2V = y2V; pa.hzV = hzV; pa.hzpV = hzpV;
  pa.o_ys = out_ys; pa.o_mean = out_mean; pa.o_logv = out_logv;
  pa.o_zs = out_zs; pa.o_zps = out_zps;
  pa.flags = bar; pa.rel = bar + 384;
  persist<<<dim3(NBLK), dim3(256), 0, stream>>>(pa);
}